// Round 4
// baseline (859.475 us; speedup 1.0000x reference)
//
#include <hip/hip_runtime.h>
#include <hip/hip_bf16.h>

typedef __hip_bfloat16 bf16;
typedef __attribute__((ext_vector_type(4))) unsigned int u32x4;
typedef __attribute__((ext_vector_type(4))) float f32x4;
typedef __attribute__((ext_vector_type(8))) short bf16x8;
#define DEV __device__ __forceinline__

// ---------------- problem constants ----------------
// N=16, C=64, H=W=160, S=25600, expanded channels 192, windows {1,3,5}

// fp32 scratch layout (offsets in floats)
constexpr int FO_Q     = 0;         // raw softmax logits, per-window concat (1239104)
constexpr int FO_SMAP  = 1239104;   // sigmoid spatial gate (1239104)
constexpr int FO_XM    = 2478208;   // per-(b,c') channel sums (560*64)
constexpr int FO_T     = 2514048;   // per-(b,c') q-weighted sums (560*64)
constexpr int FO_SIGA  = 2549888;   // per-(b,c') channel gate sigmoid(zn) (560*64)
constexpr int FO_G     = 2585728;   // per-(b,c') spatial-branch weights (560*64)
constexpr int FO_BM    = 2621568;   // per-b logit max (560)
constexpr int FO_BINV  = 2622128;   // per-b 1/sum(exp) (560)
constexpr int FO_GB    = 2622688;   // per-b spatial bias term (560)
constexpr int FO_EXPT  = 2623248;   // exp_w transposed [c*192+o] (12288)
constexpr int FO_EXPB  = 2635536;   // exp_b fp32 (192)
constexpr int FO_WBIGT = 2635728;   // combined final weight [k*64+f], k<256 (16384)
constexpr int FO_BCOMB = 2652112;   // combined final bias (64)
constexpr int FO_WFRAG = 2652176;   // bf16 A-fragment-ordered weights (16384 bf16 = 8192 f)
constexpr int FB_SIZE  = 2660368;

__device__ unsigned short g_ex_u[78643200];   // ex  [n][192ch][25600s] bf16 (win3/5 passes)
__device__ unsigned short g_ex2_u[104857600]; // ex2 [n][25600s][256ch] bf16 (k_final, win1 passes)
__device__ float          g_fb[FB_SIZE];

template<int WIN> struct WP;
template<> struct WP<1> { static constexpr int WI=0, SH=160, KH=160, K=25600, P=1,  B=16,  QOFF=0,      BOFF=0;   };
template<> struct WP<3> { static constexpr int WI=1, SH=53,  KH=54,  K=2916,  P=9,  B=144, QOFF=409600, BOFF=16;  };
template<> struct WP<5> { static constexpr int WI=2, SH=32,  KH=32,  K=1024,  P=25, B=400, QOFF=829504, BOFF=160; };

// psa-space walk helpers (used by pass kernels)
template<int WIN> DEV void decomp(int f, int& c, int& kidx, int& p) {
  constexpr int P = WP<WIN>::P, K = WP<WIN>::K;
  int m;
  if constexpr (P == 1) { p = 0; m = f; }
  else { m = f / P; p = f - m * P; }
  c = m / K; kidx = m - c * K;
}

template<int WIN> DEV void stepK(int& c, int& kidx, int& p) {  // f += K
  constexpr int K = WP<WIN>::K, P = WP<WIN>::P;
  if constexpr (P == 1) { kidx += K; }
  else {
    constexpr int KMP = K % P, KDP = K / P;
    if constexpr (KMP == 0) { kidx += KDP; }
    else { p += KMP; if (p >= P) { p -= P; kidx += KDP + 1; } else kidx += KDP; }
  }
  if (kidx >= K) { kidx -= K; ++c; }
}

template<int WIN> DEV int pix(int kidx, int p) {
  constexpr int KH = WP<WIN>::KH, SH = WP<WIN>::SH;
  if constexpr (WIN == 1) return kidx;
  int ki = kidx / KH, kj = kidx - ki * KH;
  int ph = p / WIN,  pw = p - ph * WIN;
  return (ph * SH + ki) * 160 + pw * SH + kj;
}

DEV unsigned short bfbits(float f) {
  bf16 b = __float2bfloat16(f);
  unsigned short u;
  __builtin_memcpy(&u, &b, 2);
  return u;
}

DEV float bf2f(unsigned short u) {
  bf16 b;
  __builtin_memcpy(&b, &u, 2);
  return __bfloat162float(b);
}

DEV void store8bf(bf16* p, const unsigned short* ob) {
  u32x4 v = { (unsigned)ob[0] | ((unsigned)ob[1] << 16),
              (unsigned)ob[2] | ((unsigned)ob[3] << 16),
              (unsigned)ob[4] | ((unsigned)ob[5] << 16),
              (unsigned)ob[6] | ((unsigned)ob[7] << 16) };
  *(u32x4*)p = v;
}

DEV bf16x8 as_bf16x8(u32x4 v) {
  union { u32x4 u; bf16x8 b; } x; x.u = v; return x.b;
}

// Butterfly reduce: part[c] summed across the 64 lanes of a wave; ends with
// lane l holding the total for channel bitrev6(l); one coalesced atomic.
DEV void wave_reduce64_atomic(float* dst, float (&part)[64], int lane) {
#pragma unroll
  for (int s = 0; s < 6; ++s) {
    const int m = 1 << s, half = 32 >> s;
#pragma unroll
    for (int i = 0; i < half; ++i) {
      float lo = part[i], hi = part[i + half];
      float keep = (lane & m) ? hi : lo;
      float sv   = (lane & m) ? lo : hi;
      float recv = __shfl_xor(sv, m, 64);
      part[i] = keep + recv;
    }
  }
  int chn = (int)(__brev((unsigned)lane) >> 26);
  atomicAdd(dst + chn, part[0]);
}

// ---------------- k_prep ----------------
__global__ __launch_bounds__(256)
void k_prep(const float* __restrict__ exp_w, const float* __restrict__ exp_b,
            const float* __restrict__ res_w, const float* __restrict__ res_b,
            const float* __restrict__ fus_w, const float* __restrict__ fus_b) {
  float* fb = g_fb;
  int gt = blockIdx.x * 256 + threadIdx.x;
  if (gt < 12288) {                       // Wcomb[f][oc] = sum_o fus[f][o]*res[o][oc]
    int oc = gt % 192, f = gt / 192;
    float a = 0.f;
    for (int o = 0; o < 64; ++o)
      a += fus_w[f*64+o] * res_w[o*192+oc];
    fb[FO_WBIGT + oc*64 + f] = a;
  } else if (gt < 16384) {                // rows 192..255: fus_w
    int t2 = gt - 12288; int o = t2 % 64, f = t2 / 64;
    fb[FO_WBIGT + (192+o)*64 + f] = fus_w[f*64+o];
  } else if (gt < 16448) {                // bcomb
    int f = gt - 16384;
    float a = fus_b[f];
    for (int o = 0; o < 64; ++o)
      a += fus_w[f*64+o] * res_b[o];
    fb[FO_BCOMB + f] = a;
  } else if (gt < 28736) {                // expT[c*192+o] = exp_w[o][c]
    int t3 = gt - 16448; int o = t3 % 192, c = t3 / 192;
    fb[FO_EXPT + c*192 + o] = exp_w[o*64+c];
  } else if (gt < 28928) {
    int o = gt - 28736;
    fb[FO_EXPB + o] = exp_b[o];
  } else if (gt < 28928 + 71680) {        // zero xm and t (contiguous)
    fb[FO_XM + gt - 28928] = 0.f;
  }
}

// ---------------- k_prep2: bake bf16 A-fragments for the final MFMA ----------
__global__ __launch_bounds__(256)
void k_prep2() {
  float* fb = g_fb;
  bf16* wf = (bf16*)(fb + FO_WFRAG);
  int t = blockIdx.x * 256 + threadIdx.x;     // 0..16383
  int j  = t & 7;
  int l  = (t >> 3) & 63;
  int ks = (t >> 9) & 7;
  int wv = t >> 12;
  int k = ks*32 + (l >> 4)*8 + j;
  int o = wv*16 + (l & 15);
  wf[t] = __float2bfloat16(fb[FO_WBIGT + k*64 + o]);
}

// ---------------- k_ex: ex/ex2 = conv1x1(x, exp_w, exp_b), bf16 out ----------
// waves 0..2: 64 output channels each (o0 = rg*64), writes ex (old layout)
//             and ex2 (transposed). wave 3: ex2 x-channels 192..255.
__global__ __launch_bounds__(256)
void k_ex(const float* __restrict__ x) {
  const float* fb = g_fb;
  bf16* ex  = (bf16*)g_ex_u;
  bf16* ex2 = (bf16*)g_ex2_u;
  __shared__ float xs[64*64];
  int blk = blockIdx.x; int n = blk / 400; int s0 = (blk % 400) * 64;
  int tid = threadIdx.x;
  for (int e = tid; e < 4096; e += 256) {
    int c = e >> 6, px = e & 63;
    xs[e] = x[(n*64 + c)*25600 + s0 + px];
  }
  __syncthreads();
  int px = tid & 63;
  int rg = tid >> 6;
  bf16* e2row = ex2 + (size_t)(n*25600 + s0 + px)*256;
  unsigned short ob[8];
  if (rg == 3) {                       // x passthrough channels 192..255
#pragma unroll
    for (int r = 0; r < 8; ++r) {
#pragma unroll
      for (int i = 0; i < 8; ++i)
        ob[i] = bfbits(xs[(r*8 + i)*64 + px]);
      store8bf(e2row + 192 + r*8, ob);
    }
    return;
  }
  int o0 = __builtin_amdgcn_readfirstlane(rg * 64);
  float acc[64];
#pragma unroll
  for (int j = 0; j < 64; ++j) acc[j] = fb[FO_EXPB + o0 + j];
  const float* wT = fb + FO_EXPT;
  for (int c = 0; c < 64; ++c) {
    float xv = xs[(c << 6) + px];
    const float* wr = wT + c*192 + o0;
#pragma unroll
    for (int j = 0; j < 64; ++j) acc[j] += wr[j] * xv;
  }
  bf16* eo = ex + (size_t)(n*192 + o0)*25600 + s0 + px;
#pragma unroll
  for (int j = 0; j < 64; ++j) eo[(size_t)j*25600] = __float2bfloat16(acc[j]);
#pragma unroll
  for (int r = 0; r < 8; ++r) {
#pragma unroll
    for (int i = 0; i < 8; ++i)
      ob[i] = bfbits(acc[r*8 + i]);
    store8bf(e2row + o0 + r*8, ob);
  }
}

// ---------------- k_p1all: fused logit + xm, barrier-free, all windows ------
// Each lane owns one sp and walks all 64 psa-channels.
template<int WIN, int CH, int CHUNK, int ITERS>
DEV void p1_body(int idx, const float* __restrict__ chq_w, float wqb) {
  using W = WP<WIN>;
  constexpr int K = W::K, P = W::P, CK = 64*K, WI = W::WI, QOFF = W::QOFF,
                BOFF = W::BOFF;
  float* fb = g_fb;
  const bf16* ex  = (const bf16*)g_ex_u;
  const bf16* ex2 = (const bf16*)g_ex2_u;
  int bi = idx / CH, ch = idx - bi*CH;
  int n = bi / P, bl = bi - n*P; int bg = BOFF + bi;
  int base = ch*CHUNK;
  int send = (base + CHUNK < K) ? base + CHUNK : K;
  const bf16* exn = ex + (size_t)(n*192 + WI*64)*25600;
  float* qout = fb + FO_Q + QOFF + (size_t)bi*K;
  int tid = threadIdx.x, lane = tid & 63;
  float wq[64];
#pragma unroll
  for (int j = 0; j < 64; ++j) wq[j] = chq_w[j];
  float part[64];
#pragma unroll
  for (int j = 0; j < 64; ++j) part[j] = 0.f;
  for (int it = 0; it < ITERS; ++it) {
    int sp = base + it*256 + tid;
    if (sp < send) {
      float dot = 0.f;
      if constexpr (WIN == 1) {
        // win1: channel walk is 64 contiguous bf16 at pixel sp in ex2
        const u32x4* e2 = (const u32x4*)(ex2 + (size_t)(n*25600 + sp)*256);
#pragma unroll
        for (int r = 0; r < 8; ++r) {
          u32x4 v = e2[r];
#pragma unroll
          for (int i = 0; i < 4; ++i) {
            int c = r*8 + 2*i;
            float lo = bf2f((unsigned short)(v[i] & 0xffffu));
            float hi = bf2f((unsigned short)(v[i] >> 16));
            part[c]   += lo;  dot += wq[c]   * lo;
            part[c+1] += hi;  dot += wq[c+1] * hi;
          }
        }
      } else {
        int f = bl*CK + sp;
        int c, kidx, p; decomp<WIN>(f, c, kidx, p);
#pragma unroll
        for (int j = 0; j < 64; ++j) {
          float v = __bfloat162float(exn[c*25600 + pix<WIN>(kidx, p)]);
          part[j] += v;
          dot += wq[j] * v;
          stepK<WIN>(c, kidx, p);
        }
      }
      qout[sp] = dot + wqb;
    }
  }
  wave_reduce64_atomic(fb + FO_XM + bg*64, part, lane);
}

__global__ __launch_bounds__(256, 2)
void k_p1all(const float* __restrict__ chq_w, const float* __restrict__ chq_b) {
  float wqb = chq_b[0];
  int blk = blockIdx.x;
  if (blk < 400)      p1_body<1,25,1024,4>(blk,       chq_w, wqb);
  else if (blk < 832) p1_body<3, 3, 972,4>(blk - 400, chq_w, wqb);
  else                p1_body<5, 2, 512,2>(blk - 832, chq_w, wqb);
}

// ---------------- k_bstats: per-b softmax stats + spatial branch ----------------
__global__ __launch_bounds__(256)
void k_bstats(const float* __restrict__ spq_w, const float* __restrict__ spq_b,
              const float* __restrict__ spv_w, const float* __restrict__ spv_b) {
  float* fb = g_fb;
  __shared__ float red[256]; __shared__ float sqs[32]; __shared__ float swq[32];
  int bg = blockIdx.x, tid = threadIdx.x;
  int Kk, qo, bi;
  if (bg < 16)       { Kk = 25600; qo = 0;      bi = bg;       }
  else if (bg < 160) { Kk = 2916;  qo = 409600; bi = bg - 16;  }
  else               { Kk = 1024;  qo = 829504; bi = bg - 160; }
  const float* lg = fb + FO_Q + qo + (size_t)bi*Kk;
  float m = -1e30f;
  for (int s = tid; s < Kk; s += 256) m = fmaxf(m, lg[s]);
  red[tid] = m; __syncthreads();
  for (int st = 128; st; st >>= 1) { if (tid < st) red[tid] = fmaxf(red[tid], red[tid+st]); __syncthreads(); }
  float M = red[0]; __syncthreads();
  float ss = 0.f;
  for (int s = tid; s < Kk; s += 256) ss += __expf(lg[s] - M);
  red[tid] = ss; __syncthreads();
  for (int st = 128; st; st >>= 1) { if (tid < st) red[tid] += red[tid+st]; __syncthreads(); }
  if (tid == 0) { fb[FO_BM + bg] = M; fb[FO_BINV + bg] = 1.f / red[0]; }
  const float* xm_b = fb + FO_XM + bg*64;
  float rK = 1.f / (float)Kk;
  if (tid < 32) {
    float a = spq_b[tid];
    for (int c = 0; c < 64; ++c)
      a += spq_w[tid*64 + c] * (xm_b[c] * rK);
    sqs[tid] = a;
  }
  __syncthreads();
  if (tid == 0) {
    float mx = -1e30f;
    for (int o = 0; o < 32; ++o) mx = fmaxf(mx, sqs[o]);
    float z = 0.f;
    for (int o = 0; o < 32; ++o) { float e = __expf(sqs[o] - mx); swq[o] = e; z += e; }
    float rz = 1.f / z;
    for (int o = 0; o < 32; ++o) swq[o] *= rz;
  }
  __syncthreads();
  if (tid < 64) {
    float a = 0.f;
    for (int o = 0; o < 32; ++o) a += swq[o] * spv_w[o*64 + tid];
    fb[FO_G + bg*64 + tid] = a;
  }
  if (tid == 64) {
    float gb = 0.f;
    for (int o = 0; o < 32; ++o) gb += swq[o] * spv_b[o];
    fb[FO_GB + bg] = gb;
  }
}

// ---------------- k_p2all: fused t + smap, barrier-free, all windows --------
template<int WIN, int CH, int CHUNK, int ITERS>
DEV void p2_body(int idx) {
  using W = WP<WIN>;
  constexpr int K = W::K, P = W::P, CK = 64*K, WI = W::WI, QOFF = W::QOFF,
                BOFF = W::BOFF;
  float* fb = g_fb;
  const bf16* ex  = (const bf16*)g_ex_u;
  const bf16* ex2 = (const bf16*)g_ex2_u;
  int bi = idx / CH, ch = idx - bi*CH;
  int n = bi / P, bl = bi - n*P; int bg = BOFF + bi;
  int base = ch*CHUNK;
  int send = (base + CHUNK < K) ? base + CHUNK : K;
  const bf16* exn = ex + (size_t)(n*192 + WI*64)*25600;
  const float* qin = fb + FO_Q + QOFF + (size_t)bi*K;
  float* so = fb + FO_SMAP + QOFF + (size_t)bi*K;
  float M = fb[FO_BM + bg], inv = fb[FO_BINV + bg];
  float gbs = fb[FO_GB + bg];
  int tid = threadIdx.x, lane = tid & 63;
  float gs[64];
#pragma unroll
  for (int j = 0; j < 64; ++j) gs[j] = fb[FO_G + bg*64 + j];
  float part[64];
#pragma unroll
  for (int j = 0; j < 64; ++j) part[j] = 0.f;
  for (int it = 0; it < ITERS; ++it) {
    int sp = base + it*256 + tid;
    if (sp < send) {
      float qv = __expf(qin[sp] - M) * inv;
      float dot = 0.f;
      if constexpr (WIN == 1) {
        const u32x4* e2 = (const u32x4*)(ex2 + (size_t)(n*25600 + sp)*256);
#pragma unroll
        for (int r = 0; r < 8; ++r) {
          u32x4 v = e2[r];
#pragma unroll
          for (int i = 0; i < 4; ++i) {
            int c = r*8 + 2*i;
            float lo = bf2f((unsigned short)(v[i] & 0xffffu));
            float hi = bf2f((unsigned short)(v[i] >> 16));
            part[c]   += qv * lo;  dot += gs[c]   * lo;
            part[c+1] += qv * hi;  dot += gs[c+1] * hi;
          }
        }
      } else {
        int f = bl*CK + sp;
        int c, kidx, p; decomp<WIN>(f, c, kidx, p);
#pragma unroll
        for (int j = 0; j < 64; ++j) {
          float v = __bfloat162float(exn[c*25600 + pix<WIN>(kidx, p)]);
          part[j] += qv * v;
          dot += gs[j] * v;
          stepK<WIN>(c, kidx, p);
        }
      }
      so[sp] = 1.f / (1.f + __expf(-(dot + gbs)));
    }
  }
  wave_reduce64_atomic(fb + FO_T + bg*64, part, lane);
}

__global__ __launch_bounds__(256, 2)
void k_p2all() {
  int blk = blockIdx.x;
  if (blk < 400)      p2_body<1,25,1024,4>(blk);
  else if (blk < 832) p2_body<3, 3, 972,4>(blk - 400);
  else                p2_body<5, 2, 512,2>(blk - 832);
}

// ---------------- k_zln: wz -> z -> LayerNorm -> sigA ----------------
__global__ __launch_bounds__(64)
void k_zln(const float* __restrict__ chv_w, const float* __restrict__ chv_b,
           const float* __restrict__ chz_w, const float* __restrict__ chz_b,
           const float* __restrict__ ln_g,  const float* __restrict__ ln_b) {
  float* fb = g_fb;
  __shared__ float wzs[32]; __shared__ float zsh[64]; __shared__ float mom[2];
  int bg = blockIdx.x, tid = threadIdx.x;
  const float* t_b = fb + FO_T + bg*64;
  if (tid < 32) {
    float a = chv_b[tid];
    for (int c = 0; c < 64; ++c)
      a += chv_w[tid*64 + c] * t_b[c];
    wzs[tid] = a;
  }
  __syncthreads();
  float zv = chz_b[tid];
  for (int o = 0; o < 32; ++o)
    zv += chz_w[tid*32 + o] * wzs[o];
  zsh[tid] = zv;
  __syncthreads();
  if (tid == 0) {
    float mu = 0.f;
    for (int j = 0; j < 64; ++j) mu += zsh[j];
    mu *= (1.f/64.f);
    float m2 = 0.f;
    for (int j = 0; j < 64; ++j) { float d = zsh[j] - mu; m2 += d*d; }
    m2 *= (1.f/64.f);
    mom[0] = mu; mom[1] = rsqrtf(m2 + 1e-5f);
  }
  __syncthreads();
  float zn = (zv - mom[0]) * mom[1] * ln_g[tid] + ln_b[tid];
  fb[FO_SIGA + bg*64 + tid] = 1.f / (1.f + __expf(-zn));
}

// ---------------- k_final: gates -> extT (bf16, swizzled LDS) -> MFMA conv ----
// Phase A now reads ex2[n][s][ch] contiguously: 8 x b128 per lane per wave.
template<int WIN> DEV void gate_rows3(int n, int s, int h, int w, int px,
                                      const float* __restrict__ fb,
                                      const bf16* __restrict__ e2row,
                                      bf16* extT) {
  using W = WP<WIN>;
  constexpr int SH = W::SH, KH = W::KH, K = W::K, P = W::P, WI = W::WI,
                QOFF = W::QOFF, BOFF = W::BOFF;
  const float* smap = fb + FO_SMAP + QOFF + (size_t)(n*P)*K;
  const float* sg   = fb + FO_SIGA + (size_t)(BOFF + n*P)*64;
  const u32x4* src = (const u32x4*)(e2row + WI*64);
  u32x4 vv[8];
#pragma unroll
  for (int r = 0; r < 8; ++r) vv[r] = src[r];
  int swz = (px & 7) << 3;
  unsigned short ob[8];
  if constexpr (WIN == 1) {
    float sm = smap[s];
#pragma unroll
    for (int r = 0; r < 8; ++r) {
#pragma unroll
      for (int i = 0; i < 4; ++i) {
        int c = r*8 + 2*i;
        float lo = bf2f((unsigned short)(vv[r][i] & 0xffffu));
        float hi = bf2f((unsigned short)(vv[r][i] >> 16));
        ob[2*i]   = bfbits(lo * (1.f + sg[c]   + sm));
        ob[2*i+1] = bfbits(hi * (1.f + sg[c+1] + sm));
      }
      store8bf(&extT[px*256 + ((WI*64 + r*8) ^ swz)], ob);
    }
  } else {
    int phmin = (h >= KH) ? (h - KH)/SH + 1 : 0;
    int phmax = (WIN-1 < h/SH) ? WIN-1 : h/SH;
    int pwmin = (w >= KH) ? (w - KH)/SH + 1 : 0;
    int pwmax = (WIN-1 < w/SH) ? WIN-1 : w/SH;
    int cf[4]; int s0s[4]; int np = 0;
    for (int ph = phmin; ph <= phmax; ++ph)
      for (int pw = pwmin; pw <= pwmax; ++pw) {
        int ki = h - ph*SH, kj = w - pw*SH;
        unsigned base0 = (unsigned)((ki*KH + kj)*P + ph*WIN + pw);
        unsigned q = base0 / (unsigned)K;
        cf[np] = (int)q; s0s[np] = (int)(base0 - q*(unsigned)K); ++np;
      }
    float rc = 1.f / (float)np;
    int hi4[4]; float smv[4];
#pragma unroll
    for (int t = 0; t < 4; ++t)
      if (t < np) { hi4[t] = cf[t] >> 6; smv[t] = smap[hi4[t]*K + s0s[t]]; }
#pragma unroll
    for (int r = 0; r < 8; ++r) {
#pragma unroll
      for (int cc = 0; cc < 8; ++cc) {
        float gsum = 0.f;
#pragma unroll
        for (int t = 0; t < 4; ++t) {
          if (t < np) {
            int v = cf[t];
            int h2 = v >> 6;
            if (h2 != hi4[t]) { hi4[t] = h2; smv[t] = smap[h2*K + s0s[t]]; }
            gsum += sg[v] + smv[t];
            cf[t] = v + P;
          }
        }
        unsigned wd = vv[r][cc >> 1];
        unsigned short eb = (cc & 1) ? (unsigned short)(wd >> 16)
                                     : (unsigned short)(wd & 0xffffu);
        ob[cc] = bfbits(bf2f(eb) * (1.f + gsum * rc));
      }
      store8bf(&extT[px*256 + ((WI*64 + r*8) ^ swz)], ob);
    }
  }
}

__global__ __launch_bounds__(256)
void k_final(float* __restrict__ out) {
  const float* fb = g_fb;
  const bf16* ex2 = (const bf16*)g_ex2_u;
  __shared__ __align__(16) bf16 extT[64*256];   // [px][k] swizzled, 32 KB
  int blk = blockIdx.x; int n = blk / 400; int s0 = (blk % 400) * 64;
  int tid = threadIdx.x;
  int rg = tid >> 6; int px = tid & 63;
  int s = s0 + px; int h = s / 160; int w = s - h*160;
  const bf16* e2row = ex2 + (size_t)(n*25600 + s)*256;
  if (rg == 3) {
    // x channels 192..255: straight copy (already bf16 in ex2)
    const u32x4* src = (const u32x4*)(e2row + 192);
    int swz = (px & 7) << 3;
#pragma unroll
    for (int r = 0; r < 8; ++r)
      *(u32x4*)&extT[px*256 + ((192 + r*8) ^ swz)] = src[r];
  } else if (rg == 0) gate_rows3<1>(n, s, h, w, px, fb, e2row, extT);
  else if (rg == 1)   gate_rows3<3>(n, s, h, w, px, fb, e2row, extT);
  else                gate_rows3<5>(n, s, h, w, px, fb, e2row, extT);
  __syncthreads();

  // ---- MFMA: out[o][px] = sum_k W[k][o] * extT[px][k], K=256 ----
  int wv = tid >> 6; int l = tid & 63;
  int lx = l & 15, g = l >> 4;
  const u32x4* wfA = (const u32x4*)(fb + FO_WFRAG);
  u32x4 af[8];
#pragma unroll
  for (int ks = 0; ks < 8; ++ks) af[ks] = wfA[(wv*8 + ks)*64 + l];
  f32x4 acc[4];
#pragma unroll
  for (int pt = 0; pt < 4; ++pt) acc[pt] = f32x4{0.f, 0.f, 0.f, 0.f};
#pragma unroll
  for (int ks = 0; ks < 8; ++ks) {
#pragma unroll
    for (int pt = 0; pt < 4; ++pt) {
      int pxx = pt*16 + lx;
      const u32x4* bp = (const u32x4*)&extT[pxx*256 + ((ks*32 + g*8) ^ ((pxx & 7) << 3))];
      acc[pt] = __builtin_amdgcn_mfma_f32_16x16x32_bf16(
                  as_bf16x8(af[ks]), as_bf16x8(*bp), acc[pt], 0, 0, 0);
    }
  }
  float bia[4];
#pragma unroll
  for (int r = 0; r < 4; ++r) bia[r] = fb[FO_BCOMB + wv*16 + g*4 + r];
#pragma unroll
  for (int pt = 0; pt < 4; ++pt) {
#pragma unroll
    for (int r = 0; r < 4; ++r)
      out[(size_t)(n*64 + wv*16 + g*4 + r)*25600 + s0 + pt*16 + lx] = acc[pt][r] + bia[r];
  }
}

// ---------------- launch ----------------
extern "C" void kernel_launch(void* const* d_in, const int* in_sizes, int n_in,
                              void* d_out, int out_size, void* d_ws, size_t ws_size,
                              hipStream_t stream) {
  const float* x     = (const float*)d_in[0];
  const float* exp_w = (const float*)d_in[1];
  const float* exp_b = (const float*)d_in[2];
  const float* res_w = (const float*)d_in[3];
  const float* res_b = (const float*)d_in[4];
  const float* fus_w = (const float*)d_in[5];
  const float* fus_b = (const float*)d_in[6];
  const float* chv_w = (const float*)d_in[7];
  const float* chv_b = (const float*)d_in[8];
  const float* chq_w = (const float*)d_in[9];
  const float* chq_b = (const float*)d_in[10];
  const float* chz_w = (const float*)d_in[11];
  const float* chz_b = (const float*)d_in[12];
  const float* ln_g  = (const float*)d_in[13];
  const float* ln_b  = (const float*)d_in[14];
  const float* spv_w = (const float*)d_in[15];
  const float* spv_b = (const float*)d_in[16];
  const float* spq_w = (const float*)d_in[17];
  const float* spq_b = (const float*)d_in[18];
  float* out = (float*)d_out;

  k_prep<<<393, 256, 0, stream>>>(exp_w, exp_b, res_w, res_b, fus_w, fus_b);
  k_prep2<<<64, 256, 0, stream>>>();
  k_ex<<<6400, 256, 0, stream>>>(x);

  k_p1all<<<1632, 256, 0, stream>>>(chq_w, chq_b);

  k_bstats<<<560, 256, 0, stream>>>(spq_w, spq_b, spv_w, spv_b);

  k_p2all<<<1632, 256, 0, stream>>>();

  k_zln<<<560, 64, 0, stream>>>(chv_w, chv_b, chz_w, chz_b, ln_g, ln_b);

  k_final<<<6400, 256, 0, stream>>>(out);
}